// Round 16
// baseline (1836.132 us; speedup 1.0000x reference)
//
#include <hip/hip_runtime.h>
#include <hip/hip_bf16.h>

// EntropyResidualBlock: y1 = prelu(maskconv(x,w1)+b1); y2 = prelu(maskconv(y1,w2)+b2); out = y2 + x
// 13 live taps. Implicit GEMM with mfma_f32_32x32x16_bf16.
//   conv1: D[p][o] = sum X[p+d(t)][i]*W1[t][i][o]  (A=X,B=W);  conv2: D[o][p] (A=W,B=Y).
// Layouts: X/Y packed [n][kc=24 x 16ch][h+4][w+4][16] bf16 (halo-padded);
//          W packed [t][kc][o][16] bf16 (masked).
// Round-16: R14 base + T19 sched_group_barrier pinning. Hypothesis: all schedule
// variants since R6 were neutral because hipcc sinks plain-load "prefetches" to
// their use point, normalizing every source-level pipeline to the same machine
// schedule. SGB pins emission order per granule: [2x DS_READ (xg g+3)]
// [4x MFMA (granule g)] [odd g: 2x VMEM_READ (wb refill)]. Compile-time hint,
// zero correctness risk. Barrier every 4 granules bounds each pattern region.
// All data paths byte-identical to R13/R14 (verified).

#define C_CH 384
#define HH   256
#define WWD  512
#define NN   2
#define NKC  24                    // 16-channel chunks
#define PR   260
#define PC   516
#define ICS16 (PR * PC * 16)       // shorts per (n,kc) plane = 2,146,560
#define TCOLS 144
#define PLANE_SH (4 * TCOLS * 16)  // 9216 shorts per hf sub-plane in LDS
#define TSH (2 * PLANE_SH)         // 18432 shorts = 36,864 B per buffer
#define TSTRIDE (NKC * C_CH * 16)  // 147456 shorts: t -> t+1 in wp
#define ICSTRIDE (2 * C_CH * 16)   // 12288 shorts: ic -> ic+1 (kc += 2)

typedef __attribute__((ext_vector_type(8)))  short short8;
typedef __attribute__((ext_vector_type(16))) float f32x16;

typedef const __attribute__((address_space(1))) void* gas_t;
typedef __attribute__((address_space(3))) void* las_t;

__device__ inline unsigned short f2bf(float f) {
    union { float f; unsigned int u; } v; v.f = f;
    unsigned int r = v.u + 0x7FFFu + ((v.u >> 16) & 1u);
    return (unsigned short)(r >> 16);
}

// ---------------- weights -> bf16 wp[t][kc][o][16], masked ----------------
__global__ __launch_bounds__(256) void k_prepack(const float* __restrict__ w1, const float* __restrict__ w2,
                                                 unsigned short* __restrict__ wp1, unsigned short* __restrict__ wp2) {
    int idx = blockIdx.x * 256 + threadIdx.x;
    const int TOT = 13 * NKC * C_CH * 16;
    if (idx >= TOT) return;
    int iq = idx & 15;
    int o  = (idx >> 4) % C_CH;
    int kc = (idx / (16 * C_CH)) % NKC;
    int t  = idx / (16 * C_CH * NKC);
    int i  = kc * 16 + iq;
    int kh = t < 5 ? 0 : (t < 10 ? 1 : 2);
    int kw = t < 5 ? t : (t < 10 ? t - 5 : t - 10);
    bool keep = (t != 12) || ((i / 24) <= (o / 24));
    int src = ((o * C_CH + i) * 5 + kh) * 5 + kw;
    wp1[idx] = keep ? f2bf(w1[src]) : (unsigned short)0;
    wp2[idx] = keep ? f2bf(w2[src]) : (unsigned short)0;
}

// ---------------- zero the halo borders of both packed buffers ----------------
__global__ __launch_bounds__(256) void k_zero_halo(unsigned short* __restrict__ a, unsigned short* __restrict__ b) {
    int plane = blockIdx.x;            // 0..47 (n*NKC+kc)
    const short8 z = (short8){0,0,0,0,0,0,0,0};
    for (int bi = 0; bi < 2; ++bi) {
        unsigned short* p = (bi ? b : a) + (size_t)plane * ICS16;
        for (int i = threadIdx.x; i < 4128; i += 256) {
            int r4 = i / 1032;
            int rem = i - r4 * 1032;
            int row = r4 < 2 ? r4 : 254 + r4;
            *(short8*)&p[row * (PC * 16) + rem * 8] = z;
        }
        for (int i = threadIdx.x; i < 2048; i += 256) {
            int row = 2 + (i >> 3);
            int j = i & 7;
            int col = (j < 4) ? (j >> 1) : (512 + (j >> 1));
            int q = j & 1;
            *(short8*)&p[(row * PC + col) * 16 + q * 8] = z;
        }
    }
}

// ---------------- x NCHW fp32 -> padded 16ch-chunked bf16 ----------------
__global__ __launch_bounds__(256) void k_repack_x(const float* __restrict__ x, unsigned short* __restrict__ xc) {
    int bid = blockIdx.x;              // 4096 blocks: 64 w x 384 c for one (n,h)
    int w0 = (bid & 7) << 6;
    int h  = (bid >> 3) & 255;
    int n  = bid >> 11;
    int wi = threadIdx.x & 63;
    int cq = threadIdx.x >> 6;         // 0..3 (8 channels each)
    int w  = w0 + wi;
    int inb = n * C_CH * HH * WWD + h * WWD + w;
    for (int cc = 0; cc < 12; ++cc) {
        int c0 = cc * 32 + cq * 8;
        short8 outv;
        #pragma unroll
        for (int k = 0; k < 8; ++k) {
            float f = x[inb + (c0 + k) * (HH * WWD)];
            outv[k] = (short)f2bf(f);
        }
        int kc = cc * 2 + (cq >> 1);
        int oidx = (n * NKC + kc) * ICS16 + ((h + 2) * PC + (w + 2)) * 16 + (cq & 1) * 8;
        *(short8*)&xc[oidx] = outv;
    }
}

// ---------------- masked conv via 32x32x16 MFMA ----------------
// grid 3072; 256 threads / 4 waves (wr = h-row 0/1, wc = o-half).
template<int SECOND>
__global__ __launch_bounds__(256, 2) void k_conv(const unsigned short* __restrict__ in,   // packed
                                                 const unsigned short* __restrict__ wp,
                                                 const float* __restrict__ bias,
                                                 const float* __restrict__ alpha,
                                                 const float* __restrict__ xres,
                                                 void* __restrict__ outp) {
    __shared__ __align__(16) unsigned short Xs[2][TSH];   // 2 x 36,864 B

    // ob slow within XCD chunk: 3 ob-blocks of one tile run consecutively on one XCD
    int bid0 = blockIdx.x;
    int xcd = bid0 & 7;
    int j0  = bid0 >> 3;
    int tile = xcd * 128 + j0 / 3;
    int ob   = j0 % 3;
    int n    = tile >> 9;
    int hp   = (tile >> 2) & 127;
    int wseg = tile & 3;
    int w0 = wseg << 7, o0 = ob << 7, h0 = hp << 1;

    int tid = threadIdx.x;
    int lane = tid & 63;
    int wv = tid >> 6;
    int wr = wv >> 1, wc = wv & 1;
    int lo5 = lane & 31, hi = lane >> 5;

    // staging: 36 wave-issues per buffer, 9 per wave; per-lane global offsets
    int goff[9];
    #pragma unroll
    for (int it = 0; it < 9; ++it) {
        int k = wv * 9 + it;
        int plane = k / 18;
        int s = (k % 18) * 64 + lane;
        int r = s / 288;
        int rem = s - r * 288;
        int col = rem >> 1, h16 = rem & 1;
        goff[it] = plane * ICS16 + ((h0 + r) * PC + (w0 + col)) * 16 + h16 * 8;
    }

    f32x16 acc[4][2];
    #pragma unroll
    for (int pt = 0; pt < 4; ++pt)
        #pragma unroll
        for (int ot = 0; ot < 2; ++ot)
            #pragma unroll
            for (int r = 0; r < 16; ++r) acc[pt][ot][r] = 0.f;

    const unsigned short* gbase_n = in + (size_t)n * NKC * ICS16;

    // ---- strength-reduced bases (R11) ----
    const int xlane = wr * (TCOLS * 16) + lo5 * 16 + hi * 8;
    const unsigned short* wpb = wp + (size_t)(o0 + wc * 64) * 16;
    const int wlane = lo5 * 16 + hi * 8;
    int woff0 = 0;            // slot0 scalar offset (shorts)
    int woff1 = C_CH * 16;    // slot1: hf=1 -> kc=1

    const int KH[13] = {0,0,0,0,0,1,1,1,1,1,2,2,2};
    const int KW[13] = {0,1,2,3,4,0,1,2,3,4,0,1,2};

// granule u = 2*step + phalf; step = (t,hf); granule covers pt pair {0,1} or {2,3}
#define LOAD_XG(dst, u) do {                                              \
        const int s_ = (u) >> 1, ph_ = (u) & 1;                           \
        const int t_ = s_ >> 1, hf_ = s_ & 1;                             \
        const int c0_ = hf_ * PLANE_SH + KH[t_] * (TCOLS * 16)            \
                      + KW[t_] * 16 + ph_ * 1024;                         \
        (dst)[0] = *(const short8*)&xsp[xlane + c0_];                     \
        (dst)[1] = *(const short8*)&xsp[xlane + c0_ + 512];               \
    } while (0)

#define LOAD_WB(dst, woff) do {                                           \
        (dst)[0] = *(const short8*)&wpb[(woff) + wlane];                  \
        (dst)[1] = *(const short8*)&wpb[(woff) + wlane + 512];            \
    } while (0)

    short8 wb[2][2];
    // wb for (ic=0, u=0,1) issued FIRST: ahead of all staging in the vmcnt queue
    LOAD_WB(wb[0], woff0);
    LOAD_WB(wb[1], woff1);

    // prologue: stage ic=0 into buf 0
    #pragma unroll
    for (int it = 0; it < 9; ++it)
        __builtin_amdgcn_global_load_lds((gas_t)(gbase_n + goff[it]),
                                         (las_t)&Xs[0][(wv * 9 + it) * 512], 16, 0, 0);
    __syncthreads();

    for (int ic = 0; ic < 12; ++ic) {
        const unsigned short* xsp = &Xs[ic & 1][0];
        // stage next ic into other buffer (wb for steps 0,1 already issued earlier)
        if (ic < 11) {
            const unsigned short* gb = gbase_n + (size_t)(ic + 1) * 2 * ICS16;
            #pragma unroll
            for (int it = 0; it < 9; ++it)
                __builtin_amdgcn_global_load_lds((gas_t)(gb + goff[it]),
                                                 (las_t)&Xs[(ic & 1) ^ 1][(wv * 9 + it) * 512], 16, 0, 0);
        }

        // dead tap-12: group-causal mask zeroes all its weights for these (ob,ic)
        const bool live12 = !((ob == 0 && ic >= 5) || (ob == 1 && ic >= 9));

        // granule ring-4 (32 VGPR): prefetch 3 ahead
        short8 xg[4][2];
        LOAD_XG(xg[0], 0);
        LOAD_XG(xg[1], 1);
        LOAD_XG(xg[2], 2);

        #pragma unroll
        for (int g = 0; g < 52; ++g) {
            if (g + 3 < 52) LOAD_XG(xg[(g + 3) & 3], g + 3);
            if ((g & 3) == 0) {
                // schedule-shaping barrier every 16 MFMA (516cy window)
                __builtin_amdgcn_s_barrier();
                __builtin_amdgcn_s_setprio(1);
            }
            if (g < 48 || live12) {
                const int pt0 = (g & 1) * 2;
                #pragma unroll
                for (int pi = 0; pi < 2; ++pi)
                    #pragma unroll
                    for (int ot = 0; ot < 2; ++ot) {
                        if (SECOND)
                            acc[pt0 + pi][ot] = __builtin_amdgcn_mfma_f32_32x32x16_bf16(
                                wb[(g >> 1) & 1][ot], xg[g & 3][pi], acc[pt0 + pi][ot], 0, 0, 0);
                        else
                            acc[pt0 + pi][ot] = __builtin_amdgcn_mfma_f32_32x32x16_bf16(
                                xg[g & 3][pi], wb[(g >> 1) & 1][ot], acc[pt0 + pi][ot], 0, 0, 0);
                    }
            }
            if ((g & 3) == 3) __builtin_amdgcn_s_setprio(0);
            if ((g & 1) == 1) {
                // consume-then-prefetch wb refill (identical schedule to R11/R13)
                const int s2 = g >> 1;
                if (s2 + 2 < 26) {
                    if ((s2 & 1) == 0) { woff0 += TSTRIDE; LOAD_WB(wb[0], woff0); }
                    else               { woff1 += TSTRIDE; LOAD_WB(wb[1], woff1); }
                } else {
                    if ((s2 & 1) == 0) { woff0 += ICSTRIDE - 12 * TSTRIDE; LOAD_WB(wb[0], woff0); }
                    else               { woff1 += ICSTRIDE - 12 * TSTRIDE; LOAD_WB(wb[1], woff1); }
                }
            }
            // T19 emission-order pin for this granule: prefetch ds_reads first,
            // then the 4-MFMA cluster, then (odd g) the wb global loads.
            // Compile-time hint; cannot violate data deps -> zero correctness risk.
            if (g + 3 < 52)
                __builtin_amdgcn_sched_group_barrier(0x100 /*DS_READ*/, 2, 0);
            __builtin_amdgcn_sched_group_barrier(0x8 /*MFMA*/, 4, 0);
            if ((g & 1) == 1)
                __builtin_amdgcn_sched_group_barrier(0x20 /*VMEM_READ*/, 2, 0);
        }
        __syncthreads();
    }
#undef LOAD_XG
#undef LOAD_WB

    int h = h0 + wr;
    if (!SECOND) {
        // D[p][o]: p = pt*32 + (reg&3)+8*(reg>>2)+4*hi ; o = o0+wc*64+ot*32+lo5
        unsigned short* y = (unsigned short*)outp;
        #pragma unroll
        for (int ot = 0; ot < 2; ++ot) {
            int o = o0 + wc * 64 + ot * 32 + lo5;
            float bo = bias[o], ao = alpha[o];
            int kc = o >> 4;
            int o15 = o & 15;
            size_t base = (size_t)(n * NKC + kc) * ICS16 + ((h + 2) * PC + (w0 + 2)) * 16 + o15;
            #pragma unroll
            for (int pt = 0; pt < 4; ++pt) {
                #pragma unroll
                for (int reg = 0; reg < 16; ++reg) {
                    int p = pt * 32 + (reg & 3) + 8 * (reg >> 2) + 4 * hi;
                    float v = acc[pt][ot][reg] + bo;
                    v = v >= 0.f ? v : ao * v;
                    y[base + (size_t)p * 16] = f2bf(v);
                }
            }
        }
    } else {
        // D[o][p]: o = o0+wc*64+ot*32+(reg&3)+8*(reg>>2)+4*hi ; w = w0+pt*32+lo5
        float* outf = (float*)outp;
        #pragma unroll
        for (int ot = 0; ot < 2; ++ot) {
            #pragma unroll
            for (int reg = 0; reg < 16; ++reg) {
                int o = o0 + wc * 64 + ot * 32 + (reg & 3) + 8 * (reg >> 2) + 4 * hi;
                float bo = bias[o], ao = alpha[o];
                #pragma unroll
                for (int pt = 0; pt < 4; ++pt) {
                    int w = w0 + pt * 32 + lo5;
                    float v = acc[pt][ot][reg] + bo;
                    v = v >= 0.f ? v : ao * v;
                    size_t idx = (size_t)((n * C_CH + o) * HH + h) * WWD + w;
                    outf[idx] = v + xres[idx];
                }
            }
        }
    }
}

extern "C" void kernel_launch(void* const* d_in, const int* in_sizes, int n_in,
                              void* d_out, int out_size, void* d_ws, size_t ws_size,
                              hipStream_t stream) {
    const float* x  = (const float*)d_in[0];
    const float* w1 = (const float*)d_in[1];
    const float* b1 = (const float*)d_in[2];
    const float* a1 = (const float*)d_in[3];
    const float* w2 = (const float*)d_in[4];
    const float* b2 = (const float*)d_in[5];
    const float* a2 = (const float*)d_in[6];

    const size_t PLANE_SHORTS = (size_t)NN * NKC * ICS16;       // 103,034,880 shorts
    unsigned short* xc  = (unsigned short*)d_out;               // 206,069,760 B scratch in d_out
    unsigned short* yb  = (unsigned short*)d_ws;                // 206,069,760 B
    unsigned short* wp1 = yb + PLANE_SHORTS;                    // 3,833,856 B
    unsigned short* wp2 = wp1 + 13 * NKC * C_CH * 16;           // 3,833,856 B

    k_prepack<<<(13 * NKC * C_CH * 16 + 255) / 256, 256, 0, stream>>>(w1, w2, wp1, wp2);
    k_zero_halo<<<NN * NKC, 256, 0, stream>>>(xc, yb);
    k_repack_x<<<NN * HH * (WWD / 64), 256, 0, stream>>>(x, xc);
    k_conv<0><<<3072, 256, 0, stream>>>(xc, wp1, b1, a1, nullptr, (void*)yb);
    k_conv<1><<<3072, 256, 0, stream>>>(yb, wp2, b2, a2, x, (void*)d_out);
}

// Round 17
// 1780.816 us; speedup vs baseline: 1.0311x; 1.0311x over previous
//
#include <hip/hip_runtime.h>
#include <hip/hip_bf16.h>

// EntropyResidualBlock: y1 = prelu(maskconv(x,w1)+b1); y2 = prelu(maskconv(y1,w2)+b2); out = y2 + x
// 13 live taps. Implicit GEMM with mfma_f32_32x32x16_bf16.
//   conv1: D[p][o] = sum X[p+d(t)][i]*W1[t][i][o]  (A=X,B=W);  conv2: D[o][p] (A=W,B=Y).
// Layouts: X/Y packed [n][kc=24 x 16ch][h+4][w+4][16] bf16 (halo-padded);
//          W packed [t][kc][o][16] bf16 (masked).
// Round-17: R13 exact body (best verified, 1793.8us: per-step shaping s_barrier,
// granule ring-4 xa, wb ring-2 running-offset, staging at ic top) + R14's dead
// tap-12 skip ONLY (verified numerically-identity: group-causal mask zeroes all
// tap-12 weights for (ob=0,ic>=5) and (ob=1,ic>=9); skip is a block-uniform
// scalar branch around the g=48..51 clusters). R14 bundled this skip with a
// coarser barrier cadence that measured ~-10us; this unbundles it.
// No SGB (R16: -2%), no double-barrier (R10: -2.4%), no counted vmcnt (R8: race).

#define C_CH 384
#define HH   256
#define WWD  512
#define NN   2
#define NKC  24                    // 16-channel chunks
#define PR   260
#define PC   516
#define ICS16 (PR * PC * 16)       // shorts per (n,kc) plane = 2,146,560
#define TCOLS 144
#define PLANE_SH (4 * TCOLS * 16)  // 9216 shorts per hf sub-plane in LDS
#define TSH (2 * PLANE_SH)         // 18432 shorts = 36,864 B per buffer
#define TSTRIDE (NKC * C_CH * 16)  // 147456 shorts: t -> t+1 in wp
#define ICSTRIDE (2 * C_CH * 16)   // 12288 shorts: ic -> ic+1 (kc += 2)

typedef __attribute__((ext_vector_type(8)))  short short8;
typedef __attribute__((ext_vector_type(16))) float f32x16;

typedef const __attribute__((address_space(1))) void* gas_t;
typedef __attribute__((address_space(3))) void* las_t;

__device__ inline unsigned short f2bf(float f) {
    union { float f; unsigned int u; } v; v.f = f;
    unsigned int r = v.u + 0x7FFFu + ((v.u >> 16) & 1u);
    return (unsigned short)(r >> 16);
}

// ---------------- weights -> bf16 wp[t][kc][o][16], masked ----------------
__global__ __launch_bounds__(256) void k_prepack(const float* __restrict__ w1, const float* __restrict__ w2,
                                                 unsigned short* __restrict__ wp1, unsigned short* __restrict__ wp2) {
    int idx = blockIdx.x * 256 + threadIdx.x;
    const int TOT = 13 * NKC * C_CH * 16;
    if (idx >= TOT) return;
    int iq = idx & 15;
    int o  = (idx >> 4) % C_CH;
    int kc = (idx / (16 * C_CH)) % NKC;
    int t  = idx / (16 * C_CH * NKC);
    int i  = kc * 16 + iq;
    int kh = t < 5 ? 0 : (t < 10 ? 1 : 2);
    int kw = t < 5 ? t : (t < 10 ? t - 5 : t - 10);
    bool keep = (t != 12) || ((i / 24) <= (o / 24));
    int src = ((o * C_CH + i) * 5 + kh) * 5 + kw;
    wp1[idx] = keep ? f2bf(w1[src]) : (unsigned short)0;
    wp2[idx] = keep ? f2bf(w2[src]) : (unsigned short)0;
}

// ---------------- zero the halo borders of both packed buffers ----------------
__global__ __launch_bounds__(256) void k_zero_halo(unsigned short* __restrict__ a, unsigned short* __restrict__ b) {
    int plane = blockIdx.x;            // 0..47 (n*NKC+kc)
    const short8 z = (short8){0,0,0,0,0,0,0,0};
    for (int bi = 0; bi < 2; ++bi) {
        unsigned short* p = (bi ? b : a) + (size_t)plane * ICS16;
        for (int i = threadIdx.x; i < 4128; i += 256) {
            int r4 = i / 1032;
            int rem = i - r4 * 1032;
            int row = r4 < 2 ? r4 : 254 + r4;
            *(short8*)&p[row * (PC * 16) + rem * 8] = z;
        }
        for (int i = threadIdx.x; i < 2048; i += 256) {
            int row = 2 + (i >> 3);
            int j = i & 7;
            int col = (j < 4) ? (j >> 1) : (512 + (j >> 1));
            int q = j & 1;
            *(short8*)&p[(row * PC + col) * 16 + q * 8] = z;
        }
    }
}

// ---------------- x NCHW fp32 -> padded 16ch-chunked bf16 ----------------
__global__ __launch_bounds__(256) void k_repack_x(const float* __restrict__ x, unsigned short* __restrict__ xc) {
    int bid = blockIdx.x;              // 4096 blocks: 64 w x 384 c for one (n,h)
    int w0 = (bid & 7) << 6;
    int h  = (bid >> 3) & 255;
    int n  = bid >> 11;
    int wi = threadIdx.x & 63;
    int cq = threadIdx.x >> 6;         // 0..3 (8 channels each)
    int w  = w0 + wi;
    int inb = n * C_CH * HH * WWD + h * WWD + w;
    for (int cc = 0; cc < 12; ++cc) {
        int c0 = cc * 32 + cq * 8;
        short8 outv;
        #pragma unroll
        for (int k = 0; k < 8; ++k) {
            float f = x[inb + (c0 + k) * (HH * WWD)];
            outv[k] = (short)f2bf(f);
        }
        int kc = cc * 2 + (cq >> 1);
        int oidx = (n * NKC + kc) * ICS16 + ((h + 2) * PC + (w + 2)) * 16 + (cq & 1) * 8;
        *(short8*)&xc[oidx] = outv;
    }
}

// ---------------- masked conv via 32x32x16 MFMA ----------------
// grid 3072; 256 threads / 4 waves (wr = h-row 0/1, wc = o-half).
template<int SECOND>
__global__ __launch_bounds__(256, 2) void k_conv(const unsigned short* __restrict__ in,   // packed
                                                 const unsigned short* __restrict__ wp,
                                                 const float* __restrict__ bias,
                                                 const float* __restrict__ alpha,
                                                 const float* __restrict__ xres,
                                                 void* __restrict__ outp) {
    __shared__ __align__(16) unsigned short Xs[2][TSH];   // 2 x 36,864 B

    // ob slow within XCD chunk: 3 ob-blocks of one tile run consecutively on one XCD
    int bid0 = blockIdx.x;
    int xcd = bid0 & 7;
    int j0  = bid0 >> 3;
    int tile = xcd * 128 + j0 / 3;
    int ob   = j0 % 3;
    int n    = tile >> 9;
    int hp   = (tile >> 2) & 127;
    int wseg = tile & 3;
    int w0 = wseg << 7, o0 = ob << 7, h0 = hp << 1;

    int tid = threadIdx.x;
    int lane = tid & 63;
    int wv = tid >> 6;
    int wr = wv >> 1, wc = wv & 1;
    int lo5 = lane & 31, hi = lane >> 5;

    // staging: 36 wave-issues per buffer, 9 per wave; per-lane global offsets
    int goff[9];
    #pragma unroll
    for (int it = 0; it < 9; ++it) {
        int k = wv * 9 + it;
        int plane = k / 18;
        int s = (k % 18) * 64 + lane;
        int r = s / 288;
        int rem = s - r * 288;
        int col = rem >> 1, h16 = rem & 1;
        goff[it] = plane * ICS16 + ((h0 + r) * PC + (w0 + col)) * 16 + h16 * 8;
    }

    f32x16 acc[4][2];
    #pragma unroll
    for (int pt = 0; pt < 4; ++pt)
        #pragma unroll
        for (int ot = 0; ot < 2; ++ot)
            #pragma unroll
            for (int r = 0; r < 16; ++r) acc[pt][ot][r] = 0.f;

    const unsigned short* gbase_n = in + (size_t)n * NKC * ICS16;

    // ---- strength-reduced bases (R11) ----
    const int xlane = wr * (TCOLS * 16) + lo5 * 16 + hi * 8;
    const unsigned short* wpb = wp + (size_t)(o0 + wc * 64) * 16;
    const int wlane = lo5 * 16 + hi * 8;
    int woff0 = 0;            // slot0 scalar offset (shorts)
    int woff1 = C_CH * 16;    // slot1: hf=1 -> kc=1

    const int KH[13] = {0,0,0,0,0,1,1,1,1,1,2,2,2};
    const int KW[13] = {0,1,2,3,4,0,1,2,3,4,0,1,2};

// granule u = 2*step + phalf; step = (t,hf); granule covers pt pair {0,1} or {2,3}
#define LOAD_XG(dst, u) do {                                              \
        const int s_ = (u) >> 1, ph_ = (u) & 1;                           \
        const int t_ = s_ >> 1, hf_ = s_ & 1;                             \
        const int c0_ = hf_ * PLANE_SH + KH[t_] * (TCOLS * 16)            \
                      + KW[t_] * 16 + ph_ * 1024;                         \
        (dst)[0] = *(const short8*)&xsp[xlane + c0_];                     \
        (dst)[1] = *(const short8*)&xsp[xlane + c0_ + 512];               \
    } while (0)

#define LOAD_WB(dst, woff) do {                                           \
        (dst)[0] = *(const short8*)&wpb[(woff) + wlane];                  \
        (dst)[1] = *(const short8*)&wpb[(woff) + wlane + 512];            \
    } while (0)

    short8 wb[2][2];
    // wb for (ic=0, u=0,1) issued FIRST: ahead of all staging in the vmcnt queue
    LOAD_WB(wb[0], woff0);
    LOAD_WB(wb[1], woff1);

    // prologue: stage ic=0 into buf 0
    #pragma unroll
    for (int it = 0; it < 9; ++it)
        __builtin_amdgcn_global_load_lds((gas_t)(gbase_n + goff[it]),
                                         (las_t)&Xs[0][(wv * 9 + it) * 512], 16, 0, 0);
    __syncthreads();

    for (int ic = 0; ic < 12; ++ic) {
        const unsigned short* xsp = &Xs[ic & 1][0];
        // stage next ic into other buffer (wb for steps 0,1 already issued earlier)
        if (ic < 11) {
            const unsigned short* gb = gbase_n + (size_t)(ic + 1) * 2 * ICS16;
            #pragma unroll
            for (int it = 0; it < 9; ++it)
                __builtin_amdgcn_global_load_lds((gas_t)(gb + goff[it]),
                                                 (las_t)&Xs[(ic & 1) ^ 1][(wv * 9 + it) * 512], 16, 0, 0);
        }

        // dead tap-12: group-causal mask zeroes all its weights for these (ob,ic)
        // -> skipping the g=48..51 MFMA clusters leaves acc bitwise-identical.
        const bool live12 = !((ob == 0 && ic >= 5) || (ob == 1 && ic >= 9));

        // granule ring-4 (32 VGPR): prefetch 3 ahead
        short8 xg[4][2];
        LOAD_XG(xg[0], 0);
        LOAD_XG(xg[1], 1);
        LOAD_XG(xg[2], 2);

        #pragma unroll
        for (int g = 0; g < 52; ++g) {
            if (g + 3 < 52) LOAD_XG(xg[(g + 3) & 3], g + 3);
            if ((g & 1) == 0) {
                // schedule-shaping barrier (R9/R13 cadence: every 8 MFMA)
                __builtin_amdgcn_s_barrier();
                __builtin_amdgcn_s_setprio(1);
            }
            if (g < 48 || live12) {
                const int pt0 = (g & 1) * 2;
                #pragma unroll
                for (int pi = 0; pi < 2; ++pi)
                    #pragma unroll
                    for (int ot = 0; ot < 2; ++ot) {
                        if (SECOND)
                            acc[pt0 + pi][ot] = __builtin_amdgcn_mfma_f32_32x32x16_bf16(
                                wb[(g >> 1) & 1][ot], xg[g & 3][pi], acc[pt0 + pi][ot], 0, 0, 0);
                        else
                            acc[pt0 + pi][ot] = __builtin_amdgcn_mfma_f32_32x32x16_bf16(
                                xg[g & 3][pi], wb[(g >> 1) & 1][ot], acc[pt0 + pi][ot], 0, 0, 0);
                    }
            }
            if ((g & 1) == 1) {
                __builtin_amdgcn_s_setprio(0);
                // consume-then-prefetch wb refill (identical schedule to R11/R13)
                const int s2 = g >> 1;
                if (s2 + 2 < 26) {
                    if ((s2 & 1) == 0) { woff0 += TSTRIDE; LOAD_WB(wb[0], woff0); }
                    else               { woff1 += TSTRIDE; LOAD_WB(wb[1], woff1); }
                } else {
                    if ((s2 & 1) == 0) { woff0 += ICSTRIDE - 12 * TSTRIDE; LOAD_WB(wb[0], woff0); }
                    else               { woff1 += ICSTRIDE - 12 * TSTRIDE; LOAD_WB(wb[1], woff1); }
                }
            }
        }
        __syncthreads();
    }
#undef LOAD_XG
#undef LOAD_WB

    int h = h0 + wr;
    if (!SECOND) {
        // D[p][o]: p = pt*32 + (reg&3)+8*(reg>>2)+4*hi ; o = o0+wc*64+ot*32+lo5
        unsigned short* y = (unsigned short*)outp;
        #pragma unroll
        for (int ot = 0; ot < 2; ++ot) {
            int o = o0 + wc * 64 + ot * 32 + lo5;
            float bo = bias[o], ao = alpha[o];
            int kc = o >> 4;
            int o15 = o & 15;
            size_t base = (size_t)(n * NKC + kc) * ICS16 + ((h + 2) * PC + (w0 + 2)) * 16 + o15;
            #pragma unroll
            for (int pt = 0; pt < 4; ++pt) {
                #pragma unroll
                for (int reg = 0; reg < 16; ++reg) {
                    int p = pt * 32 + (reg & 3) + 8 * (reg >> 2) + 4 * hi;
                    float v = acc[pt][ot][reg] + bo;
                    v = v >= 0.f ? v : ao * v;
                    y[base + (size_t)p * 16] = f2bf(v);
                }
            }
        }
    } else {
        // D[o][p]: o = o0+wc*64+ot*32+(reg&3)+8*(reg>>2)+4*hi ; w = w0+pt*32+lo5
        float* outf = (float*)outp;
        #pragma unroll
        for (int ot = 0; ot < 2; ++ot) {
            #pragma unroll
            for (int reg = 0; reg < 16; ++reg) {
                int o = o0 + wc * 64 + ot * 32 + (reg & 3) + 8 * (reg >> 2) + 4 * hi;
                float bo = bias[o], ao = alpha[o];
                #pragma unroll
                for (int pt = 0; pt < 4; ++pt) {
                    int w = w0 + pt * 32 + lo5;
                    float v = acc[pt][ot][reg] + bo;
                    v = v >= 0.f ? v : ao * v;
                    size_t idx = (size_t)((n * C_CH + o) * HH + h) * WWD + w;
                    outf[idx] = v + xres[idx];
                }
            }
        }
    }
}

extern "C" void kernel_launch(void* const* d_in, const int* in_sizes, int n_in,
                              void* d_out, int out_size, void* d_ws, size_t ws_size,
                              hipStream_t stream) {
    const float* x  = (const float*)d_in[0];
    const float* w1 = (const float*)d_in[1];
    const float* b1 = (const float*)d_in[2];
    const float* a1 = (const float*)d_in[3];
    const float* w2 = (const float*)d_in[4];
    const float* b2 = (const float*)d_in[5];
    const float* a2 = (const float*)d_in[6];

    const size_t PLANE_SHORTS = (size_t)NN * NKC * ICS16;       // 103,034,880 shorts
    unsigned short* xc  = (unsigned short*)d_out;               // 206,069,760 B scratch in d_out
    unsigned short* yb  = (unsigned short*)d_ws;                // 206,069,760 B
    unsigned short* wp1 = yb + PLANE_SHORTS;                    // 3,833,856 B
    unsigned short* wp2 = wp1 + 13 * NKC * C_CH * 16;           // 3,833,856 B

    k_prepack<<<(13 * NKC * C_CH * 16 + 255) / 256, 256, 0, stream>>>(w1, w2, wp1, wp2);
    k_zero_halo<<<NN * NKC, 256, 0, stream>>>(xc, yb);
    k_repack_x<<<NN * HH * (WWD / 64), 256, 0, stream>>>(x, xc);
    k_conv<0><<<3072, 256, 0, stream>>>(xc, wp1, b1, a1, nullptr, (void*)yb);
    k_conv<1><<<3072, 256, 0, stream>>>(yb, wp2, b2, a2, x, (void*)d_out);
}